// Round 4
// baseline (941.601 us; speedup 1.0000x reference)
//
#include <hip/hip_runtime.h>
#include <hip/hip_fp16.h>

#define T_ 512
#define B_ 512
#define D_ 300
#define H_ 128
#define E_ 64
#define EGO_ 12
#define DH_ 428      // D_+H_
#define BD_ 153600   // B_*D_

typedef __attribute__((ext_vector_type(2))) _Float16 half2_t;
typedef __attribute__((ext_vector_type(8))) _Float16 half8_t;
typedef __attribute__((ext_vector_type(4))) float float4_t;

__device__ __forceinline__ unsigned pack2(float a, float b) {
  __half2 h = __floats2half2_rn(a, b);
  return __builtin_bit_cast(unsigned, h);
}
__device__ __forceinline__ half8_t h8(uint4 u) {
  return __builtin_bit_cast(half8_t, u);
}
__device__ __forceinline__ float sigm(float x) {
  float e = __builtin_amdgcn_exp2f(-1.4426950408889634f * x);
  return __builtin_amdgcn_rcpf(1.0f + e);
}
__device__ __forceinline__ float tanh_(float x) {
  float e = __builtin_amdgcn_exp2f(2.8853900817779268f * x);
  return 1.0f - 2.0f * __builtin_amdgcn_rcpf(1.0f + e);
}

// ---------------- prefix sums of len_sequence -> ws ----------------
__global__ void prefix_k(const int* __restrict__ L, int* __restrict__ pfx) {
  __shared__ int s[T_];
  int t = threadIdx.x;
  s[t] = L[t];
  __syncthreads();
  for (int off = 1; off < T_; off <<= 1) {
    int v = 0;
    if (t >= off) v = s[t - off];
    __syncthreads();
    s[t] += v;
    __syncthreads();
  }
  if (t == 0) pfx[0] = 0;
  pfx[t + 1] = s[t];
}

// ---------------- LSTM scan v5: FULLY FUSED --------------------------------
// (2nd resubmission: rounds 2-3 were harness/container infra failures, not a
// kernel verdict; kernel audited for OOB/barrier-divergence/race -- clean.)
// 256 blocks x 256 threads (4 waves), batch rows b0,b0+1 at M-rows 0,4.
// The state-part of the output GEMM is fused into the epilogue. Output row
// pfx[t]+b0 needs state[b0, t, :] -- time index FIXED (=b0), batch index =
// loop var t. Each block streams the contiguous 600KB slab state[b0,:,:]
// (and b0+1) linearly, one 1200B row per step, double-buffered in LDS (sst),
// prefetched one step ahead, skipped when b0 >= len[t]. Epilogue does
// 10 state MFMAs + 4 rnn MFMAs (3 independent chains) and writes BOTH halves
// with one store. emb_state_k (the serialized 2nd kernel) is DELETED.
#define WS_ 84   // dword stride per hb row: 336B (16B-aligned), uniform bank spread
#define SST_ 160 // dword stride per sst row (150 data + zero pad)
__launch_bounds__(256, 1)
__global__ void scan_k(const float* __restrict__ state,
                       const float* __restrict__ h0,
                       const float* __restrict__ c0,
                       const int* __restrict__ lens,
                       const float* __restrict__ W_ih,
                       const float* __restrict__ W_hh,
                       const float* __restrict__ b_ih,
                       const float* __restrict__ b_hh,
                       const float* __restrict__ W_emb,
                       const float* __restrict__ b_emb,
                       const int* __restrict__ pfx,
                       float* __restrict__ out) {
  __shared__ __align__(16) unsigned hb[2][16][WS_];   // fp16x2; dw<64=h, 64..69=x, rest 0
  __shared__ __align__(16) unsigned sst[2][3][SST_];  // state rows; row2 = always-zero
  __shared__ int pfx_s[T_], len_s[T_];

  const int tid  = threadIdx.x;
  const int lane = tid & 63;
  const int w    = tid >> 6;
  const int n16  = lane & 15;
  const int quad = lane >> 4;
  const int b0   = blockIdx.x * 2;

  // ---- weight-stationary gate B-fragments: tile (c,p), 5 K-slices (K=160)
  uint4 bfr[4][2][5];
  float bias[4][2];
#pragma unroll
  for (int c = 0; c < 4; ++c) {
#pragma unroll
    for (int p = 0; p < 2; ++p) {
      const int g = c * 128 + w * 32 + 2 * n16 + p;
      bias[c][p] = b_ih[g] + b_hh[g];
#pragma unroll
      for (int s = 0; s < 5; ++s) {
        unsigned pk[4];
#pragma unroll
        for (int pp = 0; pp < 4; ++pp) {
          const int k0 = s * 32 + quad * 8 + 2 * pp;   // even
          float f0 = 0.f, f1 = 0.f;
          if (k0 < 128) { f0 = W_hh[g * H_ + k0]; f1 = W_hh[g * H_ + k0 + 1]; }
          else if (k0 < 140) {
            f0 = W_ih[g * EGO_ + (k0 - 128)];
            if (k0 + 1 < 140) f1 = W_ih[g * EGO_ + (k0 - 127)];
          }
          pk[pp] = pack2(f0, f1);
        }
        bfr[c][p][s] = make_uint4(pk[0], pk[1], pk[2], pk[3]);
      }
    }
  }
  // ---- epilogue B-fragments, e = w*16+n16: rnn half (4 slices) + state half (10)
  uint4 efr[4], sfr[10];
  const int e_ = w * 16 + n16;
  const float bemb = b_emb[e_];
#pragma unroll
  for (int s = 0; s < 4; ++s) {
    unsigned pk[4];
#pragma unroll
    for (int pp = 0; pp < 4; ++pp) {
      const int k0 = s * 32 + quad * 8 + 2 * pp;
      pk[pp] = pack2(W_emb[e_ * DH_ + D_ + k0], W_emb[e_ * DH_ + D_ + k0 + 1]);
    }
    efr[s] = make_uint4(pk[0], pk[1], pk[2], pk[3]);
  }
#pragma unroll
  for (int s = 0; s < 10; ++s) {
    unsigned pk[4];
#pragma unroll
    for (int pp = 0; pp < 4; ++pp) {
      const int k0 = s * 32 + quad * 8 + 2 * pp;   // even
      float f0 = 0.f, f1 = 0.f;
      if (k0 < D_) { f0 = W_emb[e_ * DH_ + k0]; f1 = W_emb[e_ * DH_ + k0 + 1]; }
      pk[pp] = pack2(f0, f1);
    }
    sfr[s] = make_uint4(pk[0], pk[1], pk[2], pk[3]);
  }

  // ---- LDS init: zero hb + sst fully; stage pfx/len
  for (int i = tid; i < 2 * 16 * WS_; i += 256) ((unsigned*)hb)[i] = 0u;
  for (int i = tid; i < 2 * 3 * SST_; i += 256) ((unsigned*)sst)[i] = 0u;
  for (int i = tid; i < T_; i += 256) { pfx_s[i] = pfx[i]; len_s[i] = lens[i]; }
  __syncthreads();
  if (tid < 128) {
    const int r = tid >> 6, d = tid & 63;
    float2 v = ((const float2*)(h0 + (b0 + r) * H_))[d];
    hb[0][4 * r][d] = pack2(v.x, v.y);
  }
  float2 xheld = make_float2(0.f, 0.f);
  if (tid >= 16 && tid < 28) {   // wave0/quad1 lanes do x staging
    const int j = tid - 16, row = j / 6, jj = j % 6;
    float2 v = ((const float2*)(state + (b0 + row) * D_))[jj];
    hb[0][4 * row][64 + jj] = pack2(v.x, v.y);
    xheld = ((const float2*)(state + BD_ + (b0 + row) * D_))[jj];
  }
  // ---- state-row stream setup: thread tid<150 owns float4 s_i of row srow_r
  int srow_r = 0, s_i = 0;
  size_t sbase = 0;
  float4 sheld = make_float4(0.f, 0.f, 0.f, 0.f);
  if (tid < 150) {
    srow_r = tid / 75; s_i = tid % 75;
    sbase = (size_t)(b0 + srow_r) * B_ * D_ + 4 * s_i;   // state[b0+r, t, 4i]
    if (b0 + srow_r < len_s[0])
      sheld = *(const float4*)(state + sbase);           // srow(0)
  }
  const int rsel = (n16 == 0) ? 0 : ((n16 == 4) ? 1 : 2);  // 2 = zero row
  float cst[2] = {0.f, 0.f};
  if (quad < 2) {
#pragma unroll
    for (int p = 0; p < 2; ++p)
      cst[p] = c0[(b0 + quad) * H_ + w * 32 + 2 * n16 + p];
  }
  __syncthreads();

#pragma unroll 1
  for (int t = 0; t < T_; ++t) {
    const int pb = t & 1;
    // prefetch x(t+2)
    float2 xnew = xheld;
    if (tid >= 16 && tid < 28) {
      const int j = tid - 16, row = j / 6, jj = j % 6;
      const int ttx = (t + 2 < T_) ? t + 2 : T_ - 1;
      xnew = ((const float2*)(state + (size_t)ttx * BD_ + (b0 + row) * D_))[jj];
    }
    // prefetch srow(t+1) (linear stream, skip when row won't be output)
    float4 snew = sheld;
    if (tid < 150) {
      const int tts = (t + 1 < T_) ? t + 1 : T_ - 1;
      if (b0 + srow_r < len_s[tts])
        snew = *(const float4*)(state + sbase + (size_t)tts * D_);
    }

    // ---- A-fragments from current buffer (h(t-1) | x(t) | 0)
    uint4 a[5];
#pragma unroll
    for (int s = 0; s < 5; ++s)
      a[s] = *(const uint4*)(&hb[pb][n16][s * 16 + quad * 4]);

    // ---- epilogue for t-1: BOTH halves of out row pfx[t-1]+b (3 MFMA chains)
    if (t > 0) {
      const int Lt = len_s[t - 1];
      if (b0 < Lt) {   // block-uniform skip
        float4_t er  = (float4_t){bemb, bemb, bemb, bemb};
        float4_t es0 = (float4_t){0.f, 0.f, 0.f, 0.f};
        float4_t es1 = (float4_t){0.f, 0.f, 0.f, 0.f};
#pragma unroll
        for (int s = 0; s < 4; ++s)
          er = __builtin_amdgcn_mfma_f32_16x16x32_f16(h8(a[s]), h8(efr[s]), er, 0, 0, 0);
        const unsigned* sb = &sst[pb][rsel][0];
#pragma unroll
        for (int s = 0; s < 5; ++s) {
          uint4 sa = *(const uint4*)(sb + s * 16 + quad * 4);
          es0 = __builtin_amdgcn_mfma_f32_16x16x32_f16(h8(sa), h8(sfr[s]), es0, 0, 0, 0);
        }
#pragma unroll
        for (int s = 5; s < 10; ++s) {
          uint4 sa = *(const uint4*)(sb + s * 16 + quad * 4);
          es1 = __builtin_amdgcn_mfma_f32_16x16x32_f16(h8(sa), h8(sfr[s]), es1, 0, 0, 0);
        }
        if (quad < 2 && b0 + quad < Lt)
          out[((size_t)pfx_s[t - 1] + b0 + quad) * E_ + e_] = er[0] + es0[0] + es1[0];
      }
    }

    // ---- gates(t), bias folded into C-in
    float4_t acc[4][2];
#pragma unroll
    for (int c = 0; c < 4; ++c)
#pragma unroll
      for (int p = 0; p < 2; ++p)
        acc[c][p] = (float4_t){bias[c][p], bias[c][p], bias[c][p], bias[c][p]};
#pragma unroll
    for (int s = 0; s < 5; ++s) {
      const half8_t ah = h8(a[s]);
#pragma unroll
      for (int c = 0; c < 4; ++c)
#pragma unroll
        for (int p = 0; p < 2; ++p)
          acc[c][p] = __builtin_amdgcn_mfma_f32_16x16x32_f16(ah, h8(bfr[c][p][s]), acc[c][p], 0, 0, 0);
    }

    // ---- in-lane c/h update: quad q<2 owns batch row b0+q (M-row 4q, reg 0)
    if (quad < 2) {
      float hp[2];
#pragma unroll
      for (int p = 0; p < 2; ++p) {
        const float gi = acc[0][p][0];
        const float gf = acc[1][p][0];
        const float gg = acc[2][p][0];
        const float go = acc[3][p][0];
        const float cc = sigm(gf) * cst[p] + sigm(gi) * tanh_(gg);
        cst[p] = cc;
        hp[p] = sigm(go) * tanh_(cc);
      }
      hb[1 - pb][quad * 4][w * 16 + n16] = pack2(hp[0], hp[1]);
    }
    // stage x(t+1) into next buffer
    if (tid >= 16 && tid < 28) {
      const int j = tid - 16, row = j / 6, jj = j % 6;
      hb[1 - pb][4 * row][64 + jj] = pack2(xheld.x, xheld.y);
      xheld = xnew;
    }
    // stage srow(t) into next buffer (consumed by epilogue at t+1)
    if (tid < 150) {
      unsigned* d = &sst[1 - pb][srow_r][2 * s_i];
      d[0] = pack2(sheld.x, sheld.y);
      d[1] = pack2(sheld.z, sheld.w);
      sheld = snew;
    }
    __syncthreads();   // writes to buf 1-pb visible; all reads of buf pb done
  }

  // ---- final epilogue for t = T-1 (h(511), srow(511) live in buffer 0)
  {
    const int Lt = len_s[T_ - 1];
    if (b0 < Lt) {
      float4_t er  = (float4_t){bemb, bemb, bemb, bemb};
      float4_t es0 = (float4_t){0.f, 0.f, 0.f, 0.f};
      float4_t es1 = (float4_t){0.f, 0.f, 0.f, 0.f};
#pragma unroll
      for (int s = 0; s < 4; ++s) {
        uint4 a = *(const uint4*)(&hb[0][n16][s * 16 + quad * 4]);
        er = __builtin_amdgcn_mfma_f32_16x16x32_f16(h8(a), h8(efr[s]), er, 0, 0, 0);
      }
      const unsigned* sb = &sst[0][rsel][0];
#pragma unroll
      for (int s = 0; s < 5; ++s) {
        uint4 sa = *(const uint4*)(sb + s * 16 + quad * 4);
        es0 = __builtin_amdgcn_mfma_f32_16x16x32_f16(h8(sa), h8(sfr[s]), es0, 0, 0, 0);
      }
#pragma unroll
      for (int s = 5; s < 10; ++s) {
        uint4 sa = *(const uint4*)(sb + s * 16 + quad * 4);
        es1 = __builtin_amdgcn_mfma_f32_16x16x32_f16(h8(sa), h8(sfr[s]), es1, 0, 0, 0);
      }
      if (quad < 2 && b0 + quad < Lt)
        out[((size_t)pfx_s[T_ - 1] + b0 + quad) * E_ + e_] = er[0] + es0[0] + es1[0];
    }
  }
}

extern "C" void kernel_launch(void* const* d_in, const int* in_sizes, int n_in,
                              void* d_out, int out_size, void* d_ws, size_t ws_size,
                              hipStream_t stream) {
  const float* state = (const float*)d_in[0];
  const float* h0    = (const float*)d_in[1];
  const float* c0    = (const float*)d_in[2];
  const int*   lens  = (const int*)d_in[3];
  const float* W_ih  = (const float*)d_in[4];
  const float* W_hh  = (const float*)d_in[5];
  const float* b_ih  = (const float*)d_in[6];
  const float* b_hh  = (const float*)d_in[7];
  const float* W_emb = (const float*)d_in[8];
  const float* b_emb = (const float*)d_in[9];
  float* out = (float*)d_out;
  int* pfx = (int*)d_ws;            // 513 ints

  prefix_k<<<1, T_, 0, stream>>>(lens, pfx);
  scan_k<<<B_ / 2, 256, 0, stream>>>(state, h0, c0, lens, W_ih, W_hh, b_ih, b_hh,
                                     W_emb, b_emb, pfx, out);
}

// Round 7
// 859.105 us; speedup vs baseline: 1.0960x; 1.0960x over previous
//
#include <hip/hip_runtime.h>
#include <hip/hip_fp16.h>

#define T_ 512
#define B_ 512
#define D_ 300
#define H_ 128
#define E_ 64
#define EGO_ 12
#define DH_ 428      // D_+H_
#define BD_ 153600   // B_*D_

typedef __attribute__((ext_vector_type(2))) _Float16 half2_t;
typedef __attribute__((ext_vector_type(8))) _Float16 half8_t;
typedef __attribute__((ext_vector_type(4))) float float4_t;

__device__ __forceinline__ unsigned pack2(float a, float b) {
  __half2 h = __floats2half2_rn(a, b);
  return __builtin_bit_cast(unsigned, h);
}
__device__ __forceinline__ half8_t h8(uint4 u) {
  return __builtin_bit_cast(half8_t, u);
}
__device__ __forceinline__ float sigm(float x) {
  float e = __builtin_amdgcn_exp2f(-1.4426950408889634f * x);
  return __builtin_amdgcn_rcpf(1.0f + e);
}
__device__ __forceinline__ float tanh_(float x) {
  float e = __builtin_amdgcn_exp2f(2.8853900817779268f * x);
  return 1.0f - 2.0f * __builtin_amdgcn_rcpf(1.0f + e);
}

// ---------------- prefix sums of len_sequence -> ws ----------------
__global__ void prefix_k(const int* __restrict__ L, int* __restrict__ pfx) {
  __shared__ int s[T_];
  int t = threadIdx.x;
  s[t] = L[t];
  __syncthreads();
  for (int off = 1; off < T_; off <<= 1) {
    int v = 0;
    if (t >= off) v = s[t - off];
    __syncthreads();
    s[t] += v;
    __syncthreads();
  }
  if (t == 0) pfx[0] = 0;
  pfx[t + 1] = s[t];
}

// ---------------- LSTM scan v6.1: fused, GROUP-AMORTIZED epilogue -----------
// (resubmission: round-6 bench was a container-acquisition infra failure; the
// only delta vs the v6 NaN run is the restored one-time zeroing below.)
// v6 NaN fix: sst staging writes dwords 0..149 but epilogue slice s=9 reads
// dwords up to 159 (k=288..319). Without zeroing, the k>=300 pad of VALID rows
// is fp16 garbage -> NaN*0 = NaN in all output rows. Restore the ONE-TIME full
// zeroing of hh+sst (per-step writes never touch the pads, so they stay zero).
// Design (from v5 diagnosis): epilogue batched over G=4 steps -- h(t), srow(t)
// staged at M-row 2*(t&3)+br; ONE epilogue per 4 steps emits 8 output rows
// (C rows 0..7 = quads 0,1 x regs 0..3) -> 14 MFMA + 14 b128 reads per 4 steps
// instead of per step. State stream prefetch depth 2 (covers ~900cy HBM
// latency). SST_=164 (==4 mod 32, conflict-minimal). Gates path = the 416us
// round-1 structure.
#define WS_ 84    // hb row stride (dwords)
#define HH_ 84    // hh row stride
#define SST_ 164  // sst row stride (== 4 mod 32: conflict-minimal n16-row reads)
__launch_bounds__(256, 1)
__global__ void scan_k(const float* __restrict__ state,
                       const float* __restrict__ h0,
                       const float* __restrict__ c0,
                       const int* __restrict__ lens,
                       const float* __restrict__ W_ih,
                       const float* __restrict__ W_hh,
                       const float* __restrict__ b_ih,
                       const float* __restrict__ b_hh,
                       const float* __restrict__ W_emb,
                       const float* __restrict__ b_emb,
                       const int* __restrict__ pfx,
                       float* __restrict__ out) {
  __shared__ __align__(16) unsigned hb[2][16][WS_];    // gates A: h(t-1)|x(t)|0
  __shared__ __align__(16) unsigned hh[2][16][HH_];    // group history: hs[t0+dt] at row 2dt+br
  __shared__ __align__(16) unsigned sst[2][16][SST_];  // group history: srow(t0+dt) at row 2dt+br
  __shared__ int pfx_s[T_], len_s[T_];

  const int tid  = threadIdx.x;
  const int lane = tid & 63;
  const int w    = tid >> 6;
  const int n16  = lane & 15;
  const int quad = lane >> 4;
  const int b0   = blockIdx.x * 2;

  // ---- weight-stationary gate B-fragments: tile (c,p), 5 K-slices (K=160)
  uint4 bfr[4][2][5];
  float bias[4][2];
#pragma unroll
  for (int c = 0; c < 4; ++c) {
#pragma unroll
    for (int p = 0; p < 2; ++p) {
      const int g = c * 128 + w * 32 + 2 * n16 + p;
      bias[c][p] = b_ih[g] + b_hh[g];
#pragma unroll
      for (int s = 0; s < 5; ++s) {
        unsigned pk[4];
#pragma unroll
        for (int pp = 0; pp < 4; ++pp) {
          const int k0 = s * 32 + quad * 8 + 2 * pp;   // even
          float f0 = 0.f, f1 = 0.f;
          if (k0 < 128) { f0 = W_hh[g * H_ + k0]; f1 = W_hh[g * H_ + k0 + 1]; }
          else if (k0 < 140) {
            f0 = W_ih[g * EGO_ + (k0 - 128)];
            if (k0 + 1 < 140) f1 = W_ih[g * EGO_ + (k0 - 127)];
          }
          pk[pp] = pack2(f0, f1);
        }
        bfr[c][p][s] = make_uint4(pk[0], pk[1], pk[2], pk[3]);
      }
    }
  }
  // ---- epilogue B-fragments, e = w*16+n16: rnn half (4 slices) + state half (10)
  uint4 efr[4], sfr[10];
  const int e_ = w * 16 + n16;
  const float bemb = b_emb[e_];
#pragma unroll
  for (int s = 0; s < 4; ++s) {
    unsigned pk[4];
#pragma unroll
    for (int pp = 0; pp < 4; ++pp) {
      const int k0 = s * 32 + quad * 8 + 2 * pp;
      pk[pp] = pack2(W_emb[e_ * DH_ + D_ + k0], W_emb[e_ * DH_ + D_ + k0 + 1]);
    }
    efr[s] = make_uint4(pk[0], pk[1], pk[2], pk[3]);
  }
#pragma unroll
  for (int s = 0; s < 10; ++s) {
    unsigned pk[4];
#pragma unroll
    for (int pp = 0; pp < 4; ++pp) {
      const int k0 = s * 32 + quad * 8 + 2 * pp;   // even
      float f0 = 0.f, f1 = 0.f;
      if (k0 < D_) { f0 = W_emb[e_ * DH_ + k0]; f1 = W_emb[e_ * DH_ + k0 + 1]; }
      pk[pp] = pack2(f0, f1);
    }
    sfr[s] = make_uint4(pk[0], pk[1], pk[2], pk[3]);
  }

  // ---- LDS init: zero hb + hh + sst FULLY (pads must be 0; per-step writes
  // only ever touch rows 0..7 dwords 0..149/0..63, so pads stay zero).
  for (int i = tid; i < 2 * 16 * WS_; i += 256) ((unsigned*)hb)[i] = 0u;
  for (int i = tid; i < 2 * 16 * HH_; i += 256) ((unsigned*)hh)[i] = 0u;
  for (int i = tid; i < 2 * 16 * SST_; i += 256) ((unsigned*)sst)[i] = 0u;
  for (int i = tid; i < T_; i += 256) { pfx_s[i] = pfx[i]; len_s[i] = lens[i]; }
  __syncthreads();
  if (tid < 128) {
    const int r = tid >> 6, d = tid & 63;
    float2 v = ((const float2*)(h0 + (b0 + r) * H_))[d];
    hb[0][4 * r][d] = pack2(v.x, v.y);
  }
  float2 xheld = make_float2(0.f, 0.f);
  if (tid >= 16 && tid < 28) {   // wave0/quad1 lanes do x staging
    const int j = tid - 16, row = j / 6, jj = j % 6;
    float2 v = ((const float2*)(state + (b0 + row) * D_))[jj];
    hb[0][4 * row][64 + jj] = pack2(v.x, v.y);
    xheld = ((const float2*)(state + BD_ + (b0 + row) * D_))[jj];
  }
  // ---- state-row stream, prefetch DEPTH 2: thread tid<150 owns (srow_r, s_i)
  int srow_r = 0, s_i = 0;
  size_t sbase = 0;
  float4 sheld0 = make_float4(0.f, 0.f, 0.f, 0.f);
  float4 sheld1 = make_float4(0.f, 0.f, 0.f, 0.f);
  if (tid < 150) {
    srow_r = tid / 75; s_i = tid % 75;
    sbase = (size_t)(b0 + srow_r) * B_ * D_ + 4 * s_i;   // state[b0+r, t, 4i]
    if (b0 + srow_r < len_s[0]) sheld0 = *(const float4*)(state + sbase);
    if (b0 + srow_r < len_s[1]) sheld1 = *(const float4*)(state + sbase + D_);
  }
  float cst[2] = {0.f, 0.f};
  if (quad < 2) {
#pragma unroll
    for (int p = 0; p < 2; ++p)
      cst[p] = c0[(b0 + quad) * H_ + w * 32 + 2 * n16 + p];
  }
  __syncthreads();

#pragma unroll 1
  for (int t = 0; t < T_; ++t) {
    const int pb = t & 1;          // hb parity
    const int gp = (t >> 2) & 1;   // group parity (write side)
    // prefetch x(t+2)
    float2 xnew = xheld;
    if (tid >= 16 && tid < 28) {
      const int j = tid - 16, row = j / 6, jj = j % 6;
      const int ttx = (t + 2 < T_) ? t + 2 : T_ - 1;
      xnew = ((const float2*)(state + (size_t)ttx * BD_ + (b0 + row) * D_))[jj];
    }
    // prefetch srow(t+2) (depth 2 -> ~2 iteration bodies of latency cover)
    float4 snew = make_float4(0.f, 0.f, 0.f, 0.f);
    if (tid < 150) {
      const int tts = (t + 2 < T_) ? t + 2 : T_ - 1;
      if (b0 + srow_r < len_s[tts])
        snew = *(const float4*)(state + sbase + (size_t)tts * D_);
    }

    // ---- A-fragments from current buffer (h(t-1) | x(t) | 0)
    uint4 a[5];
#pragma unroll
    for (int s = 0; s < 5; ++s)
      a[s] = *(const uint4*)(&hb[pb][n16][s * 16 + quad * 4]);

    // ---- GROUP EPILOGUE: once per 4 steps, 8 output rows (segs t-4..t-1)
    if ((t & 3) == 0 && t > 0) {
      const int rb = 1 - gp;   // buffer holding the finished group
      float4_t er  = (float4_t){bemb, bemb, bemb, bemb};
      float4_t es0 = (float4_t){0.f, 0.f, 0.f, 0.f};
      float4_t es1 = (float4_t){0.f, 0.f, 0.f, 0.f};
#pragma unroll
      for (int s = 0; s < 4; ++s) {
        uint4 ha = *(const uint4*)(&hh[rb][n16][s * 16 + quad * 4]);
        er = __builtin_amdgcn_mfma_f32_16x16x32_f16(h8(ha), h8(efr[s]), er, 0, 0, 0);
      }
#pragma unroll
      for (int s = 0; s < 5; ++s) {
        uint4 sa = *(const uint4*)(&sst[rb][n16][s * 16 + quad * 4]);
        es0 = __builtin_amdgcn_mfma_f32_16x16x32_f16(h8(sa), h8(sfr[s]), es0, 0, 0, 0);
      }
#pragma unroll
      for (int s = 5; s < 10; ++s) {
        uint4 sa = *(const uint4*)(&sst[rb][n16][s * 16 + quad * 4]);
        es1 = __builtin_amdgcn_mfma_f32_16x16x32_f16(h8(sa), h8(sfr[s]), es1, 0, 0, 0);
      }
      if (quad < 2) {
#pragma unroll
        for (int r = 0; r < 4; ++r) {
          const int R  = quad * 4 + r;      // tile row 0..7 = 2*dt + br
          const int seg = (t - 4) + (R >> 1);
          const int br  = R & 1;
          if (b0 + br < len_s[seg])
            out[((size_t)pfx_s[seg] + b0 + br) * E_ + e_] = er[r] + es0[r] + es1[r];
        }
      }
    }

    // ---- gates(t), bias folded into C-in
    float4_t acc[4][2];
#pragma unroll
    for (int c = 0; c < 4; ++c)
#pragma unroll
      for (int p = 0; p < 2; ++p)
        acc[c][p] = (float4_t){bias[c][p], bias[c][p], bias[c][p], bias[c][p]};
#pragma unroll
    for (int s = 0; s < 5; ++s) {
      const half8_t ah = h8(a[s]);
#pragma unroll
      for (int c = 0; c < 4; ++c)
#pragma unroll
        for (int p = 0; p < 2; ++p)
          acc[c][p] = __builtin_amdgcn_mfma_f32_16x16x32_f16(ah, h8(bfr[c][p][s]), acc[c][p], 0, 0, 0);
    }

    // ---- in-lane c/h update: quad q<2 owns batch row b0+q (M-row 4q, reg 0)
    if (quad < 2) {
      float hp[2];
#pragma unroll
      for (int p = 0; p < 2; ++p) {
        const float gi = acc[0][p][0];
        const float gf = acc[1][p][0];
        const float gg = acc[2][p][0];
        const float go = acc[3][p][0];
        const float cc = sigm(gf) * cst[p] + sigm(gi) * tanh_(gg);
        cst[p] = cc;
        hp[p] = sigm(go) * tanh_(cc);
      }
      const unsigned hpk = pack2(hp[0], hp[1]);
      hb[1 - pb][quad * 4][w * 16 + n16] = hpk;           // next-step gates A
      hh[gp][2 * (t & 3) + quad][w * 16 + n16] = hpk;     // group history hs[t]
    }
    // stage x(t+1) into next gates buffer
    if (tid >= 16 && tid < 28) {
      const int j = tid - 16, row = j / 6, jj = j % 6;
      hb[1 - pb][4 * row][64 + jj] = pack2(xheld.x, xheld.y);
      xheld = xnew;
    }
    // stage srow(t) into group buffer row 2*(t&3)+r; shift depth-2 pipeline
    if (tid < 150) {
      unsigned* d = &sst[gp][2 * (t & 3) + srow_r][2 * s_i];
      d[0] = pack2(sheld0.x, sheld0.y);
      d[1] = pack2(sheld0.z, sheld0.w);
      sheld0 = sheld1;
      sheld1 = snew;
    }
    __syncthreads();
  }

  // ---- final group epilogue: segs T-4..T-1 live in buffer 1-((T_>>2)&1) = 1
  {
    const int rb = 1 - ((T_ >> 2) & 1);
    float4_t er  = (float4_t){bemb, bemb, bemb, bemb};
    float4_t es0 = (float4_t){0.f, 0.f, 0.f, 0.f};
    float4_t es1 = (float4_t){0.f, 0.f, 0.f, 0.f};
#pragma unroll
    for (int s = 0; s < 4; ++s) {
      uint4 ha = *(const uint4*)(&hh[rb][n16][s * 16 + quad * 4]);
      er = __builtin_amdgcn_mfma_f32_16x16x32_f16(h8(ha), h8(efr[s]), er, 0, 0, 0);
    }
#pragma unroll
    for (int s = 0; s < 5; ++s) {
      uint4 sa = *(const uint4*)(&sst[rb][n16][s * 16 + quad * 4]);
      es0 = __builtin_amdgcn_mfma_f32_16x16x32_f16(h8(sa), h8(sfr[s]), es0, 0, 0, 0);
    }
#pragma unroll
    for (int s = 5; s < 10; ++s) {
      uint4 sa = *(const uint4*)(&sst[rb][n16][s * 16 + quad * 4]);
      es1 = __builtin_amdgcn_mfma_f32_16x16x32_f16(h8(sa), h8(sfr[s]), es1, 0, 0, 0);
    }
    if (quad < 2) {
#pragma unroll
      for (int r = 0; r < 4; ++r) {
        const int R  = quad * 4 + r;
        const int seg = (T_ - 4) + (R >> 1);
        const int br  = R & 1;
        if (b0 + br < len_s[seg])
          out[((size_t)pfx_s[seg] + b0 + br) * E_ + e_] = er[r] + es0[r] + es1[r];
      }
    }
  }
}

extern "C" void kernel_launch(void* const* d_in, const int* in_sizes, int n_in,
                              void* d_out, int out_size, void* d_ws, size_t ws_size,
                              hipStream_t stream) {
  const float* state = (const float*)d_in[0];
  const float* h0    = (const float*)d_in[1];
  const float* c0    = (const float*)d_in[2];
  const int*   lens  = (const int*)d_in[3];
  const float* W_ih  = (const float*)d_in[4];
  const float* W_hh  = (const float*)d_in[5];
  const float* b_ih  = (const float*)d_in[6];
  const float* b_hh  = (const float*)d_in[7];
  const float* W_emb = (const float*)d_in[8];
  const float* b_emb = (const float*)d_in[9];
  float* out = (float*)d_out;
  int* pfx = (int*)d_ws;            // 513 ints

  prefix_k<<<1, T_, 0, stream>>>(lens, pfx);
  scan_k<<<B_ / 2, 256, 0, stream>>>(state, h0, c0, lens, W_ih, W_hh, b_ih, b_hh,
                                     W_emb, b_emb, pfx, out);
}